// Round 1
// baseline (72.249 us; speedup 1.0000x reference)
//
#include <hip/hip_runtime.h>
#include <hip/hip_bf16.h>
#include <math.h>

#define BB 2048
#define DD 512
#define NS 7
#define KK 1024  // 2*DD concatenated

typedef __attribute__((ext_vector_type(8))) short short8;
typedef __attribute__((ext_vector_type(4))) float floatx4;

__device__ inline unsigned short f2bf(float f) {
  unsigned int u = __float_as_uint(f);
  u += 0x7FFFu + ((u >> 16) & 1u);   // round-to-nearest-even
  return (unsigned short)(u >> 16);
}

__device__ inline float wave_reduce_sum(float v) {
#pragma unroll
  for (int off = 32; off > 0; off >>= 1) v += __shfl_down(v, off, 64);
  return v;
}
__device__ inline float wave_reduce_max(float v) {
#pragma unroll
  for (int off = 32; off > 0; off >>= 1) v = fmaxf(v, __shfl_down(v, off, 64));
  return v;
}
// blockDim.x == 256 (4 waves) assumed
__device__ inline float block_reduce_sum256(float v, float* sbuf) {
  v = wave_reduce_sum(v);
  if ((threadIdx.x & 63) == 0) sbuf[threadIdx.x >> 6] = v;
  __syncthreads();
  float r = sbuf[0] + sbuf[1] + sbuf[2] + sbuf[3];
  __syncthreads();
  return r;
}
__device__ inline float block_reduce_max256(float v, float* sbuf) {
  v = wave_reduce_max(v);
  if ((threadIdx.x & 63) == 0) sbuf[threadIdx.x >> 6] = v;
  __syncthreads();
  float r = fmaxf(fmaxf(sbuf[0], sbuf[1]), fmaxf(sbuf[2], sbuf[3]));
  __syncthreads();
  return r;
}

// ---------------------------------------------------------------------------
// Kernel 1: per-query prep.  Acat[q][0..511]=W=exp(-qls); Acat[q][512..1023]=-2*qm*W
// qterm[q] = sum_d qm^2 * W
__global__ void prep_query(const float* __restrict__ qmean,
                           const float* __restrict__ qls,
                           unsigned short* __restrict__ Acat,
                           float* __restrict__ qterm) {
  __shared__ float sbuf[4];
  const int q = blockIdx.x, tid = threadIdx.x;
  const float* xm = qmean + q * DD;
  const float* xl = qls + q * DD;
  float x0 = xm[tid], x1 = xm[tid + 256];
  float ss = block_reduce_sum256(x0 * x0 + x1 * x1, sbuf);
  float inv = 1.0f / fmaxf(sqrtf(ss), 1e-12f);
  float l0 = xl[tid], l1 = xl[tid + 256];
  float w0 = expf(-l0), w1 = expf(-l1);
  float n0 = x0 * inv, n1 = x1 * inv;
  unsigned short* arow = Acat + q * KK;
  arow[tid]            = f2bf(w0);
  arow[tid + 256]      = f2bf(w1);
  arow[DD + tid]       = f2bf(-2.0f * n0 * w0);
  arow[DD + tid + 256] = f2bf(-2.0f * n1 * w1);
  float qt = block_reduce_sum256(n0 * n0 * w0 + n1 * n1 * w1, sbuf);
  if (tid == 0) qterm[q] = qt;
}

// ---------------------------------------------------------------------------
// Kernel 2: per-target prep. Bcat[t][0..511]=S2, Bcat[t][512..1023]=S1
// S1 = mean_s(tm + eps*sig), S2 = mean_s(tm + eps*sig)^2
__global__ void prep_target(const float* __restrict__ tmean,
                            const float* __restrict__ tls,
                            const float* __restrict__ eps,
                            unsigned short* __restrict__ Bcat) {
  __shared__ float sbuf[4];
  const int t = blockIdx.x, tid = threadIdx.x;
  const float* xm = tmean + t * DD;
  const float* xl = tls + t * DD;
  float x0 = xm[tid], x1 = xm[tid + 256];
  float ss = block_reduce_sum256(x0 * x0 + x1 * x1, sbuf);
  float inv = 1.0f / fmaxf(sqrtf(ss), 1e-12f);
  unsigned short* brow = Bcat + t * KK;
  const float i7 = 1.0f / 7.0f;
#pragma unroll
  for (int h = 0; h < 2; ++h) {
    int d = tid + h * 256;
    float tm = (h ? x1 : x0) * inv;
    float sig = expf(xl[d]);
    float se = 0.f, se2 = 0.f;
#pragma unroll
    for (int s = 0; s < NS; ++s) {
      float e = eps[(t * NS + s) * DD + d];
      se += e;
      se2 += e * e;
    }
    float s1 = tm + sig * se * i7;
    float s2 = tm * tm + 2.0f * tm * sig * se * i7 + sig * sig * se2 * i7;
    brow[d] = f2bf(s2);
    brow[DD + d] = f2bf(s1);
  }
}

// ---------------------------------------------------------------------------
// Kernel 3: loc[q][t] = -0.5 * ( sum_k Acat[q,k]*Bcat[t,k] + qterm[q] )
// 128x128 tile, 4 waves (2x2), each wave 64x64 via 4x4 frags of 16x16x32 bf16.
__global__ __launch_bounds__(256) void gemm_loc(
    const unsigned short* __restrict__ Acat,
    const unsigned short* __restrict__ Bcat,
    const float* __restrict__ qterm,
    float* __restrict__ loc) {
  __shared__ short As[128 * 72];  // BK=64, pad to 72 (stride 144B -> conflict-free)
  __shared__ short Bs[128 * 72];
  const int tid = threadIdx.x;
  const int brow = blockIdx.y * 128;  // q
  const int bcol = blockIdx.x * 128;  // t
  const int wid = tid >> 6, lane = tid & 63;
  const int wr = wid >> 1, wc = wid & 1;
  const int fr = lane & 15, kg = lane >> 4;  // fragment row, k-group

  floatx4 acc[4][4];
#pragma unroll
  for (int m = 0; m < 4; ++m)
#pragma unroll
    for (int n = 0; n < 4; ++n) acc[m][n] = (floatx4){0.f, 0.f, 0.f, 0.f};

  for (int kt = 0; kt < KK; kt += 64) {
    __syncthreads();
#pragma unroll
    for (int i = 0; i < 4; ++i) {
      int c = tid + 256 * i;        // 0..1023 chunks of 8 bf16
      int r = c >> 3;               // row 0..127
      int k8 = (c & 7) * 8;         // col 0..56
      *reinterpret_cast<short8*>(&As[r * 72 + k8]) =
          *reinterpret_cast<const short8*>(&Acat[(brow + r) * KK + kt + k8]);
      *reinterpret_cast<short8*>(&Bs[r * 72 + k8]) =
          *reinterpret_cast<const short8*>(&Bcat[(bcol + r) * KK + kt + k8]);
    }
    __syncthreads();
#pragma unroll
    for (int kk = 0; kk < 64; kk += 32) {
      short8 af[4], bf[4];
#pragma unroll
      for (int m = 0; m < 4; ++m)
        af[m] = *reinterpret_cast<const short8*>(
            &As[(wr * 64 + m * 16 + fr) * 72 + kk + 8 * kg]);
#pragma unroll
      for (int n = 0; n < 4; ++n)
        bf[n] = *reinterpret_cast<const short8*>(
            &Bs[(wc * 64 + n * 16 + fr) * 72 + kk + 8 * kg]);
#pragma unroll
      for (int m = 0; m < 4; ++m)
#pragma unroll
        for (int n = 0; n < 4; ++n)
          acc[m][n] = __builtin_amdgcn_mfma_f32_16x16x32_bf16(af[m], bf[n],
                                                              acc[m][n], 0, 0, 0);
    }
  }
  // epilogue: C row = 4*kg + reg, col = fr
#pragma unroll
  for (int m = 0; m < 4; ++m) {
#pragma unroll
    for (int r4 = 0; r4 < 4; ++r4) {
      int row = brow + wr * 64 + m * 16 + kg * 4 + r4;
      float qt = qterm[row];
#pragma unroll
      for (int n = 0; n < 4; ++n) {
        int col = bcol + wc * 64 + n * 16 + fr;
        loc[row * BB + col] = -0.5f * (acc[m][n][r4] + qt);
      }
    }
  }
}

// ---------------------------------------------------------------------------
// Kernel 4a/4b: column max M[t] = max_q loc[q][t]   (2-stage for parallelism)
__global__ void colmax_part(const float* __restrict__ loc, float* __restrict__ Mpart) {
  const int t = blockIdx.x * 256 + threadIdx.x;
  const int q0 = blockIdx.y * 128;
  float m = -3.402823466e38f;
  for (int q = q0; q < q0 + 128; ++q) m = fmaxf(m, loc[q * BB + t]);
  Mpart[blockIdx.y * BB + t] = m;
}
__global__ void colmax_fin(const float* __restrict__ Mpart, float* __restrict__ M) {
  const int t = blockIdx.x * 256 + threadIdx.x;
  float m = -3.402823466e38f;
#pragma unroll
  for (int i = 0; i < 16; ++i) m = fmaxf(m, Mpart[i * BB + t]);
  M[t] = m;
}

// ---------------------------------------------------------------------------
// Kernel 5: per-row logsumexp + diagonal -> rowval[q] = (loc[q,q]-M[q]) - lse
__global__ void row_lse(const float* __restrict__ loc, const float* __restrict__ M,
                        float* __restrict__ rowval) {
  __shared__ float sbuf[4];
  __shared__ float lg[BB];  // 8 KB: logits of this row
  const int q = blockIdx.x, tid = threadIdx.x;
  float m = -3.402823466e38f;
#pragma unroll
  for (int i = 0; i < 8; ++i) {
    int t = tid + i * 256;
    float x = loc[q * BB + t] - M[t];
    lg[t] = x;
    m = fmaxf(m, x);
  }
  m = block_reduce_max256(m, sbuf);  // includes barrier -> lg[] visible
  float s = 0.f;
#pragma unroll
  for (int i = 0; i < 8; ++i) s += expf(lg[tid + i * 256] - m);
  s = block_reduce_sum256(s, sbuf);
  if (tid == 0) {
    float lse = m + logf(s);
    rowval[q] = lg[q] - lse;
  }
}

// ---------------------------------------------------------------------------
// Kernel 6: loss = -mean_q rowval[q]
__global__ void final_loss(const float* __restrict__ rowval, float* __restrict__ out) {
  __shared__ float sbuf[4];
  const int tid = threadIdx.x;
  float s = 0.f;
#pragma unroll
  for (int i = 0; i < 8; ++i) s += rowval[tid + i * 256];
  s = block_reduce_sum256(s, sbuf);
  if (tid == 0) out[0] = -s * (1.0f / (float)BB);
}

// ---------------------------------------------------------------------------
extern "C" void kernel_launch(void* const* d_in, const int* in_sizes, int n_in,
                              void* d_out, int out_size, void* d_ws, size_t ws_size,
                              hipStream_t stream) {
  const float* qmean = (const float*)d_in[0];
  const float* qls   = (const float*)d_in[1];
  // d_in[2] query_z: cancels in score-max + log_softmax (broadcast on target axis)
  const float* tmean = (const float*)d_in[3];
  const float* tls   = (const float*)d_in[4];
  // d_in[5] target_z: unused by reference
  const float* eps   = (const float*)d_in[6];

  char* ws = (char*)d_ws;
  unsigned short* Acat = (unsigned short*)(ws + 0);          // 4 MB
  unsigned short* Bcat = (unsigned short*)(ws + 4194304);    // 4 MB
  float* qterm = (float*)(ws + 8388608);                     // 8 KB
  float* Mcol  = (float*)(ws + 8396800);                     // 8 KB
  float* rowval= (float*)(ws + 8404992);                     // 8 KB
  float* Mpart = (float*)(ws + 8413184);                     // 128 KB
  float* loc   = (float*)(ws + 8544256);                     // 16 MB

  prep_query<<<BB, 256, 0, stream>>>(qmean, qls, Acat, qterm);
  prep_target<<<BB, 256, 0, stream>>>(tmean, tls, eps, Bcat);
  gemm_loc<<<dim3(16, 16), 256, 0, stream>>>(Acat, Bcat, qterm, loc);
  colmax_part<<<dim3(8, 16), 256, 0, stream>>>(loc, Mpart);
  colmax_fin<<<8, 256, 0, stream>>>(Mpart, Mcol);
  row_lse<<<BB, 256, 0, stream>>>(loc, Mcol, rowval);
  final_loss<<<1, 256, 0, stream>>>(rowval, (float*)d_out);
}